// Round 6
// baseline (587.226 us; speedup 1.0000x reference)
//
#include <hip/hip_runtime.h>
#include <stdint.h>

#define KVOL 27
#define CIN  32
#define COUT 32

typedef short bf16x8 __attribute__((ext_vector_type(8)));
typedef float f32x4  __attribute__((ext_vector_type(4)));

// ---------------------------------------------------------------------------
// kmap_valid layout probe (1-byte bool vs int32). flag[0]=1 -> int32 layout.
// ---------------------------------------------------------------------------
__global__ void detect_valid_layout(const uint8_t* __restrict__ valid_bytes,
                                    int* __restrict__ flag) {
    __shared__ int s_sum;
    if (threadIdx.x == 0) s_sum = 0;
    __syncthreads();
    int local = 0;
    for (int g = threadIdx.x; g < 1024; g += 256) {
        local += valid_bytes[4 * g + 1] + valid_bytes[4 * g + 2] + valid_bytes[4 * g + 3];
    }
    atomicAdd(&s_sum, local);
    __syncthreads();
    if (threadIdx.x == 0) flag[0] = (s_sum == 0) ? 1 : 0;
}

__device__ inline unsigned short f2bf(float f) {
    unsigned int u = __float_as_uint(f);
    return (unsigned short)((u + 0x7fffu + ((u >> 16) & 1u)) >> 16);
}

// X (N*32 fp32) -> Xb (N*32 bf16), 8 elements per thread, 16B stores.
// Also zero-fills row N (the "invalid gather" target row).
__global__ __launch_bounds__(256)
void convert_x(const float* __restrict__ X, short* __restrict__ Xb, int n8) {
    int i = blockIdx.x * blockDim.x + threadIdx.x;
    if (i < 4) {                       // row N = bf16x8 slots n8 .. n8+3
        bf16x8 z = {};
        *((bf16x8*)Xb + (size_t)n8 + i) = z;
    }
    if (i >= n8) return;
    const float4* p = (const float4*)X + 2 * (size_t)i;
    float4 f0 = p[0], f1 = p[1];
    bf16x8 o;
    o[0] = (short)f2bf(f0.x); o[1] = (short)f2bf(f0.y);
    o[2] = (short)f2bf(f0.z); o[3] = (short)f2bf(f0.w);
    o[4] = (short)f2bf(f1.x); o[5] = (short)f2bf(f1.y);
    o[6] = (short)f2bf(f1.z); o[7] = (short)f2bf(f1.w);
    *((bf16x8*)Xb + (size_t)i) = o;
}

// W (27,ci,co) fp32 -> Wt (27,co,ci) bf16
__global__ __launch_bounds__(256)
void convert_w(const float* __restrict__ W, short* __restrict__ Wt) {
    int i = blockIdx.x * blockDim.x + threadIdx.x; // i over 27*32*32
    if (i >= KVOL * CIN * COUT) return;
    int k  = i >> 10;
    int co = (i >> 5) & 31;
    int ci = i & 31;
    Wt[i] = (short)f2bf(W[k * 1024 + ci * 32 + co]);
}

// ---------------------------------------------------------------------------
// MFMA main, v6: ZERO-LDS flat 27-tap pipeline.
//   Evidence (R5): dur == bytes/3.7TB/s; FETCH invariant ~900MB; BW responds
//   to concurrency (R3 85%occ -> 4.25TB/s). So: remove the per-chunk stage
//   stalls + LDS round-trip and smooth the issue pattern.
//   - Per-lane direct idx/valid loads: lane(col,quad) loads idx[k][base+g*16
//     +col] itself; 4 duplicate-address lanes coalesce, total bytes unchanged.
//   - jv-ring depth 3, issued 6 taps ahead of use (~700cyc HBM cover).
//   - gather buffers a0/a1/a2 (depth 3), issued 3 taps ahead of MFMA.
//   - no barriers, no chunks, no LDS; occupancy purely VGPR-bound.
//
// A-frag (16x16x32): lane holds A[m=lane&15][k=(lane>>4)*8+j]  (16B gather)
// B-frag:            lane holds B[k=(lane>>4)*8+j][n=lane&15]  -> Wt[k][n][k0+j]
// C/D:               D[m=(lane>>4)*4+r][n=lane&15]
// ---------------------------------------------------------------------------
struct JV4 { int j[4]; int v[4]; };

__global__ __launch_bounds__(256)
void sparse_conv_mfma(const short* __restrict__ Xb,
                      const short* __restrict__ Wt,
                      const float* __restrict__ bias,
                      const int* __restrict__ idx,
                      const uint8_t* __restrict__ validb,
                      const int* __restrict__ flag,
                      float* __restrict__ out, int N) {
    const int lane = threadIdx.x & 63;
    const int wave = threadIdx.x >> 6;
    const int col  = lane & 15;
    const int quad = lane >> 4;
    const int base = blockIdx.x * 256 + wave * 64;

    const int vshift = (flag[0] != 0) ? 2 : 0;   // int32 layout -> byte0 of each int
    const char* XbB = (const char*)Xb;
    const size_t Nsz = (size_t)N;
    const unsigned zoff = (unsigned)N << 6;      // byte offset of the zero row

    // Per-group row this lane is responsible for (clamped), + in-bounds flag.
    int rc[4], ok[4];
#pragma unroll
    for (int g = 0; g < 4; ++g) {
        const int r = base + g * 16 + col;
        ok[g] = (r < N) ? 1 : 0;
        rc[g] = (r < N) ? r : (N - 1);
    }

    f32x4 acc[4][2] = {};
    bf16x8 a0[4], a1[4], a2[4];
    JV4 jv0, jv1, jv2;

#define JVLOAD(S, t)                                                          \
    do {                                                                      \
        if ((t) < KVOL) {                                                     \
            const size_t ko = (size_t)(t) * Nsz;                              \
            _Pragma("unroll") for (int g = 0; g < 4; ++g) {                   \
                S.j[g] = __builtin_nontemporal_load(idx + ko + rc[g]);        \
                S.v[g] = (int)__builtin_nontemporal_load(                     \
                    validb + ((ko + (size_t)rc[g]) << vshift));               \
            }                                                                 \
        }                                                                     \
    } while (0)

#define GI(S, A, t)                                                           \
    do {                                                                      \
        if ((t) < KVOL) {                                                     \
            _Pragma("unroll") for (int g = 0; g < 4; ++g) {                   \
                const unsigned mm = (ok[g] & (S.v[g] != 0))                   \
                                        ? ((unsigned)S.j[g] << 6)             \
                                        : zoff;                               \
                A[g] = *(const bf16x8*)(XbB + (size_t)mm + quad * 16);        \
            }                                                                 \
        }                                                                     \
    } while (0)

#define TAP(A, t)                                                             \
    do {                                                                      \
        if ((t) < KVOL) {                                                     \
            const bf16x8 b0 =                                                 \
                *(const bf16x8*)(Wt + ((t) * 1024 + col * 32 + quad * 8));    \
            const bf16x8 b1 =                                                 \
                *(const bf16x8*)(Wt +                                         \
                                 ((t) * 1024 + (col + 16) * 32 + quad * 8));  \
            _Pragma("unroll") for (int g = 0; g < 4; ++g) {                   \
                acc[g][0] = __builtin_amdgcn_mfma_f32_16x16x32_bf16(          \
                    A[g], b0, acc[g][0], 0, 0, 0);                            \
                acc[g][1] = __builtin_amdgcn_mfma_f32_16x16x32_bf16(          \
                    A[g], b1, acc[g][1], 0, 0, 0);                            \
            }                                                                 \
        }                                                                     \
    } while (0)

    // Prologue: fill jv ring (taps 0..2), then gather taps 0..2 while
    // issuing jv for taps 3..5.
    JVLOAD(jv0, 0); JVLOAD(jv1, 1); JVLOAD(jv2, 2);
    GI(jv0, a0, 0); JVLOAD(jv0, 3);
    GI(jv1, a1, 1); JVLOAD(jv1, 4);
    GI(jv2, a2, 2); JVLOAD(jv2, 5);

    // Steady state: per tap t -> MFMA(t), gather-issue(t+3) (consumes jv
    // issued 6 taps earlier), jv-issue(t+6) (into the slot just consumed).
#pragma unroll
    for (int tb = 0; tb < KVOL; tb += 3) {
        TAP(a0, tb + 0); GI(jv0, a0, tb + 3); JVLOAD(jv0, tb + 6);
        TAP(a1, tb + 1); GI(jv1, a1, tb + 4); JVLOAD(jv1, tb + 7);
        TAP(a2, tb + 2); GI(jv2, a2, tb + 5); JVLOAD(jv2, tb + 8);
    }

#undef JVLOAD
#undef GI
#undef TAP

    const float bv0 = bias[col];
    const float bv1 = bias[col + 16];
#pragma unroll
    for (int g = 0; g < 4; ++g) {
#pragma unroll
        for (int rr = 0; rr < 4; ++rr) {
            const int row = base + g * 16 + quad * 4 + rr;
            if (row < N) {
                __builtin_nontemporal_store(acc[g][0][rr] + bv0,
                                            &out[(size_t)row * COUT + col]);
                __builtin_nontemporal_store(acc[g][1][rr] + bv1,
                                            &out[(size_t)row * COUT + col + 16]);
            }
        }
    }
}

// ---------------------------------------------------------------------------
// Fallback fp32 kernel (used only if ws_size is too small for bf16 staging).
// ---------------------------------------------------------------------------
__global__ __launch_bounds__(256)
void sparse_conv_fp32(const float* __restrict__ X,
                      const float* __restrict__ W,
                      const float* __restrict__ B,
                      const int* __restrict__ idx,
                      const uint8_t* __restrict__ validb,
                      const int* __restrict__ flag,
                      float* __restrict__ out,
                      int N) {
    const int n = blockIdx.x * blockDim.x + threadIdx.x;
    if (n >= N) return;
    const bool int_layout = (flag[0] != 0);
    const int* validi = (const int*)validb;
    float acc[COUT];
#pragma unroll
    for (int co = 0; co < COUT; ++co) acc[co] = B[co];
    for (int k = 0; k < KVOL; ++k) {
        const size_t kn = (size_t)k * (size_t)N + (size_t)n;
        const int v = int_layout ? validi[kn] : (int)validb[kn];
        if (v) {
            const int j = idx[kn];
            const float4* xp = (const float4*)(X + (size_t)j * CIN);
            float xr[CIN];
#pragma unroll
            for (int q = 0; q < 8; ++q) {
                float4 t = xp[q];
                xr[4 * q + 0] = t.x; xr[4 * q + 1] = t.y;
                xr[4 * q + 2] = t.z; xr[4 * q + 3] = t.w;
            }
            const float* __restrict__ Wk = W + k * CIN * COUT;
#pragma unroll
            for (int ci = 0; ci < CIN; ++ci) {
                const float xv = xr[ci];
#pragma unroll
                for (int co = 0; co < COUT; ++co) acc[co] += xv * Wk[ci * COUT + co];
            }
        }
    }
    float4* op = (float4*)(out + (size_t)n * COUT);
#pragma unroll
    for (int q = 0; q < 8; ++q)
        op[q] = make_float4(acc[4 * q + 0], acc[4 * q + 1], acc[4 * q + 2], acc[4 * q + 3]);
}

extern "C" void kernel_launch(void* const* d_in, const int* in_sizes, int n_in,
                              void* d_out, int out_size, void* d_ws, size_t ws_size,
                              hipStream_t stream) {
    const float*   X      = (const float*)d_in[0];   // (N, 32)
    const float*   W      = (const float*)d_in[1];   // (27, 32, 32)
    const float*   B      = (const float*)d_in[2];   // (32,)
    const int*     idx    = (const int*)d_in[3];     // (27, N)
    const uint8_t* validb = (const uint8_t*)d_in[4]; // (27, N)

    const int N = in_sizes[0] / CIN;

    const size_t xb_bytes = (size_t)(N + 1) * CIN * sizeof(short); // +1 zero row
    const size_t wt_bytes = (size_t)KVOL * CIN * COUT * sizeof(short);
    const size_t need     = xb_bytes + wt_bytes + 256;

    if (ws_size >= need) {
        short* Xb  = (short*)d_ws;
        short* Wt  = (short*)((char*)d_ws + xb_bytes);
        int*   flag = (int*)((char*)d_ws + xb_bytes + wt_bytes);

        detect_valid_layout<<<1, 256, 0, stream>>>(validb, flag);

        const int n8 = (N * CIN) / 8;
        convert_x<<<(n8 + 255) / 256, 256, 0, stream>>>(X, Xb, n8);
        convert_w<<<(KVOL * CIN * COUT + 255) / 256, 256, 0, stream>>>(W, Wt);

        const int blocks = (N + 255) / 256;
        sparse_conv_mfma<<<blocks, 256, 0, stream>>>(Xb, Wt, B, idx, validb,
                                                     flag, (float*)d_out, N);
    } else {
        int* flag = (int*)d_ws;
        detect_valid_layout<<<1, 256, 0, stream>>>(validb, flag);
        const int blocks = (N + 255) / 256;
        sparse_conv_fp32<<<blocks, 256, 0, stream>>>(X, W, B, idx, validb,
                                                     flag, (float*)d_out, N);
    }
}